// Round 12
// baseline (165.634 us; speedup 1.0000x reference)
//
#include <hip/hip_runtime.h>

#define NODE_IN 64
#define EDGE_IN 32
#define GLOBAL_IN 32
#define HID 128
#define EOUT 32

typedef float f32x4 __attribute__((ext_vector_type(4)));
typedef short s16x8 __attribute__((ext_vector_type(8)));
typedef unsigned short u16x8 __attribute__((ext_vector_type(8)));

// LDS: Xbuf[2] f32 [32 rows x 160 f32] (row = 640 B = 40 x 16B chunks:
//   src 0-15 | dst 16-31 | ea 32-39, chunk-XOR swizzled within 8-groups)
// + H bf16 [32][128] (256 B rows, chunk-XOR) + u bf16 [128][32].
#define XB0   0
#define XB1   20480
#define HOFF  40960
#define UOFF  49152
#define LDSZ  57344

#define GLOADD(dst, ptr)  asm volatile("global_load_dword %0, %1, off" : "=v"(dst) : "v"(ptr))
#define WAIT_VM7()  asm volatile("s_waitcnt vmcnt(7)"  ::: "memory")
#define WAIT_VM11() asm volatile("s_waitcnt vmcnt(11)" ::: "memory")

__device__ __forceinline__ unsigned short f2bf(float f) {
  __bf16 h = (__bf16)f;
  return __builtin_bit_cast(unsigned short, h);
}

__device__ __forceinline__ s16x8 cvt8(f32x4 a, f32x4 b) {
  u16x8 v = { f2bf(a[0]), f2bf(a[1]), f2bf(a[2]), f2bf(a[3]),
              f2bf(b[0]), f2bf(b[1]), f2bf(b[2]), f2bf(b[3]) };
  return __builtin_bit_cast(s16x8, v);
}

__device__ __forceinline__ void bar_lds() {   // lgkm-only barrier
  asm volatile("s_waitcnt lgkmcnt(0)" ::: "memory");
  __builtin_amdgcn_s_barrier();
  asm volatile("" ::: "memory");
}

// async global->LDS DMA, 16 B/lane (dest = wave-uniform base + lane*16)
__device__ __forceinline__ void glds16(const float* g, const char* l) {
  __builtin_amdgcn_global_load_lds(
      (const __attribute__((address_space(1))) unsigned int*)g,
      (__attribute__((address_space(3))) unsigned int*)l, 16, 0, 0);
}

// ---- prep: W1/W2 -> bf16 MFMA B-fragment table in d_ws (56 frags x 1KB) ----
// f<48 (kk=f>>3, wd=(f>>1)&3, nt=f&1): paired cols 32wd+2lr+nt.
// f>=48 (q=f-48, kk=q>>1, nf=q&1): cols 16nf+lr.
__global__ __launch_bounds__(64) void prep_w(const float* __restrict__ W1,
                                             const float* __restrict__ W2,
                                             unsigned short* __restrict__ wsf) {
  const int f = blockIdx.x, l = threadIdx.x;
  const int lg = l >> 4, lr = l & 15;
  u16x8 v;
  if (f < 48) {
    const int kk = f >> 3, wd = (f >> 1) & 3, nt = f & 1;
#pragma unroll
    for (int j = 0; j < 8; ++j)
      v[j] = f2bf(W1[(32*kk + 8*lg + j)*HID + 32*wd + 2*lr + nt]);
  } else {
    const int q = f - 48, kk = q >> 1, nf = q & 1;
#pragma unroll
    for (int j = 0; j < 8; ++j)
      v[j] = f2bf(W2[(32*kk + 8*lg + j)*EOUT + 16*nf + lr]);
  }
  *(u16x8*)&wsf[f*512 + l*8] = v;
}

// ============================================================================
// Continuous-pressure pipeline: 32-edge tiles, X f32 via global_load_lds into
// a 2-deep circular LDS buffer (zero staging VGPR/VALU), counted vmcnt(11)
// (5 glds + 2 ebp + 4 stores per tile) so the VM queue NEVER drains — loads
// for tile t+2 are issued while t is computed, landing during t+1. The
// burst-then-idle HBM rhythm of R5/R8 (2.3 TB/s) becomes continuous issue.
// Source pre-swizzle (chunk ^= row&7 within 8-groups) + same XOR on reads
// (rule #21). u bf16 staged once/block; bb indices ping-pong 2 tiles deep.
// ============================================================================
__global__ __launch_bounds__(256) void edge_mlp(
    const float* __restrict__ srcp, const float* __restrict__ dstp,
    const float* __restrict__ eap, const float* __restrict__ up,
    const int* __restrict__ ebp, const unsigned short* __restrict__ wsf,
    const float* __restrict__ b1, const float* __restrict__ b2,
    float* __restrict__ outp, int E, int ntiles)
{
  __shared__ __align__(16) char SM[LDSZ];

  const int t = threadIdx.x;
  const int wid = t >> 6;
  const int lane = t & 63;
  const int g = lane >> 4;
  const int r16 = lane & 15;
  const int mf = wid >> 1, nf = wid & 1;
  const int Em1 = E - 1;

  // ---- weights from table (coalesced b128) ----
  s16x8 w1f[6][2];
#pragma unroll
  for (int kk = 0; kk < 6; ++kk) {
    w1f[kk][0] = *(const s16x8*)&wsf[(kk*8 + wid*2 + 0)*512 + lane*8];
    w1f[kk][1] = *(const s16x8*)&wsf[(kk*8 + wid*2 + 1)*512 + lane*8];
  }
  s16x8 w2f4[4];
#pragma unroll
  for (int kk = 0; kk < 4; ++kk)
    w2f4[kk] = *(const s16x8*)&wsf[(48 + kk*2 + nf)*512 + lane*8];
  const float b1v0 = b1[32*wid + 2*r16];
  const float b1v1 = b1[32*wid + 2*r16 + 1];
  const float b2v  = b2[16*nf + r16];

  // ---- stage u once: f32[128][32] -> bf16 [128][32] ----
  {
    const int row = t >> 1, half = t & 1;
    const float* pu = up + row * GLOBAL_IN + half * 16;
    const f32x4 u0 = *(const f32x4*)pu,       u1 = *(const f32x4*)(pu + 4);
    const f32x4 u2 = *(const f32x4*)(pu + 8), u3 = *(const f32x4*)(pu + 12);
    *(s16x8*)(SM + UOFF + row*64 + half*32)      = cvt8(u0, u1);
    *(s16x8*)(SM + UOFF + row*64 + half*32 + 16) = cvt8(u2, u3);
  }

  // ---- per-thread glds mapping (5 instrs/wave, pre-swizzled source) ----
  int rowk[5]; const char* gp[5]; int pitchB[5];
#pragma unroll
  for (int k = 0; k < 5; ++k) {
    const int i  = 5*wid + k;
    const int C0 = i*64 + lane;          // global chunk slot 0..1279
    const int row = C0 / 40;
    const int ch  = C0 - row*40;
    const int chs = (ch & ~7) | ((ch & 7) ^ (row & 7));   // source pre-swizzle
    rowk[k] = row;
    if (ch < 16)      { gp[k] = (const char*)srcp + chs*16;      pitchB[k] = 256; }
    else if (ch < 32) { gp[k] = (const char*)dstp + (chs-16)*16; pitchB[k] = 256; }
    else              { gp[k] = (const char*)eap  + (chs-32)*16; pitchB[k] = 128; }
  }

  auto issue_stage = [&](int tb, int xb) {
#pragma unroll
    for (int k = 0; k < 5; ++k) {
      const int gr = min(tb + rowk[k], Em1);
      glds16((const float*)(gp[k] + (size_t)gr * pitchB[k]),
             SM + xb + (5*wid + k)*1024);
    }
  };

  int tile = blockIdx.x;
  const int TS = gridDim.x;
  int bbA0, bbA1, bbB0, bbB1;

  // ---- prologue: 2 tiles in flight ----
  issue_stage(tile*32, XB0);
  GLOADD(bbA0, (ebp + min(tile*32 + r16,      Em1)));
  GLOADD(bbA1, (ebp + min(tile*32 + 16 + r16, Em1)));
  issue_stage((tile + TS)*32, XB1);
  GLOADD(bbB0, (ebp + min((tile + TS)*32 + r16,      Em1)));
  GLOADD(bbB1, (ebp + min((tile + TS)*32 + 16 + r16, Em1)));
  WAIT_VM7();                              // tile0's 7 landed (tile1 in flight)
  __builtin_amdgcn_sched_barrier(0);
  bar_lds();                               // + u staged

  auto body = [&](int tt, int xb, int& bb0, int& bb1) {
    const int tb = tt * 32;

    // ---- layer 1: 2 m-frags x 2 n-frags, K=192 (X f32->bf16 at consume) ----
    f32x4 acc[2][2];
    {
      const f32x4 z = {0.f, 0.f, 0.f, 0.f};
      acc[0][0] = z; acc[0][1] = z; acc[1][0] = z; acc[1][1] = z;
    }
#pragma unroll
    for (int mi = 0; mi < 2; ++mi) {
      const char* Xr = SM + xb + (16*mi + r16)*640;
      const int sw = r16 & 7;
      s16x8 fr[6];
#pragma unroll
      for (int kk = 0; kk < 5; ++kk) {
        const f32x4 a = *(const f32x4*)(Xr + (8*kk + (((2*g)  ) ^ sw))*16);
        const f32x4 b = *(const f32x4*)(Xr + (8*kk + (((2*g)|1) ^ sw))*16);
        fr[kk] = cvt8(a, b);
      }
      const int bbv = mi ? bb1 : bb0;
      fr[5] = *(const s16x8*)(SM + UOFF + bbv*64 + g*16);
#pragma unroll
      for (int kk = 0; kk < 6; ++kk) {
        acc[mi][0] = __builtin_amdgcn_mfma_f32_16x16x32_bf16(fr[kk], w1f[kk][0], acc[mi][0], 0, 0, 0);
        acc[mi][1] = __builtin_amdgcn_mfma_f32_16x16x32_bf16(fr[kk], w1f[kk][1], acc[mi][1], 0, 0, 0);
      }
    }

    // ---- epilogue: +b1, relu, packed dword -> swizzled H ----
#pragma unroll
    for (int mi = 0; mi < 2; ++mi) {
#pragma unroll
      for (int j = 0; j < 4; ++j) {
        const float h0 = fmaxf(acc[mi][0][j] + b1v0, 0.f);
        const float h1 = fmaxf(acc[mi][1][j] + b1v1, 0.f);
        const unsigned int pk = (unsigned int)f2bf(h0) |
                                ((unsigned int)f2bf(h1) << 16);
        const int row = 16*mi + 4*g + j;
        const int ch = (4*wid + (r16 >> 2)) ^ ((4*g + j) & 7);
        *(unsigned int*)(SM + HOFF + row*256 + ch*16 + (r16 & 3)*4) = pk;
      }
    }
    bar_lds();                 // B1: H ready; X(tt) reads done

    // ---- refill this buffer with tile tt+2TS (flies over L2 + next L1) ----
    issue_stage((tt + 2*TS)*32, xb);
    GLOADD(bb0, (ebp + min((tt + 2*TS)*32 + r16,      Em1)));
    GLOADD(bb1, (ebp + min((tt + 2*TS)*32 + 16 + r16, Em1)));

    // ---- layer 2: rows 16mf..+16, cols 16nf..+16, K=128 ----
    f32x4 acc2;
    { const f32x4 z = {0.f, 0.f, 0.f, 0.f}; acc2 = z; }
#pragma unroll
    for (int kk = 0; kk < 4; ++kk) {
      const int ch = (4*kk + g) ^ (r16 & 7);
      const s16x8 ah = *(const s16x8*)(SM + HOFF + (16*mf + r16)*256 + ch*16);
      acc2 = __builtin_amdgcn_mfma_f32_16x16x32_bf16(ah, w2f4[kk], acc2, 0, 0, 0);
    }
#pragma unroll
    for (int j = 0; j < 4; ++j) {
      const int m = tb + 16*mf + 4*g + j;
      if (m < E) outp[(size_t)m*EOUT + 16*nf + r16] = acc2[j] + b2v;
    }

    // counted drain: newest 11 (this tile's 5 glds + 2 ebp + 4 stores) may
    // stay in flight; everything older (NEXT tile's buffer+bb) has landed.
    WAIT_VM11();
    __builtin_amdgcn_sched_barrier(0);
    bar_lds();                 // B2: H reads done; next buffer ready
  };

  for (; tile < ntiles; tile += 2*TS) {
    body(tile, XB0, bbA0, bbA1);
    if (tile + TS < ntiles)
      body(tile + TS, XB1, bbB0, bbB1);
  }
}

extern "C" void kernel_launch(void* const* d_in, const int* in_sizes, int n_in,
                              void* d_out, int out_size, void* d_ws, size_t ws_size,
                              hipStream_t stream) {
  const float* srcp = (const float*)d_in[0];
  const float* dstp = (const float*)d_in[1];
  const float* eap  = (const float*)d_in[2];
  const float* up   = (const float*)d_in[3];
  const int*   ebp  = (const int*)d_in[4];
  const float* W1   = (const float*)d_in[5];
  const float* b1   = (const float*)d_in[6];
  const float* W2   = (const float*)d_in[7];
  const float* b2   = (const float*)d_in[8];
  float* outp = (float*)d_out;
  unsigned short* wsf = (unsigned short*)d_ws;

  const int E = in_sizes[0] / NODE_IN;
  const int ntiles = (E + 31) / 32;
  const int grid = ntiles < 512 ? ntiles : 512;   // 2 persistent blocks/CU

  prep_w<<<56, 64, 0, stream>>>(W1, W2, wsf);
  edge_mlp<<<grid, 256, 0, stream>>>(srcp, dstp, eap, up, ebp, wsf, b1, b2,
                                     outp, E, ntiles);
}